// Round 5
// baseline (1111.199 us; speedup 1.0000x reference)
//
#include <hip/hip_runtime.h>
#include <stdint.h>

// N_NODES=500000, N_EDGES=16000000, V_DIM=2, E_DIM=3. MLP: 5->50->20->1.
//
// Pipeline (deterministic, no global atomics in the hot path):
//  K0 hist: per-wg (16K edges) LDS histogram of 512-node buckets ->
//           counts[w][NB] (coalesced row write).
//  S1/S2:   two-level exclusive scan in (bucket-major, then wg) order ->
//           counts[] becomes per-(wg,bucket) row prefix, bucket_base[],
//           row_total[] (= per-bucket count).
//  K1 bin:  per-wg LDS counting sort (hist -> block scan -> rank -> inv[])
//           then emit 16B records {e0,e1,e2,tgt} in bucket-sorted order.
//           Consecutive sorted slots = consecutive global slots within a
//           (wg,bucket) run (~270 B) -> near-full-line coalesced writes
//           (R4's 2.1x write amplification came from random 16B scatter).
//  K2 agg:  one wg per bucket streams its records, LDS fp32 atomics into a
//           6 KB slice, writes table[N,4] coalesced.
//  K3 mlp:  per-node 5->50->20->1, ALL loops fully unrolled (dynamic
//           indexing of h2[] forced scratch traffic before -> suspect for
//           the ~280us residual).
// Edge range is chunked if ws can't hold all 256 MB of records.

#define BSHIFT 9
#define BNODES 512
#define NB 1024            // max buckets -> n_nodes <= 524288
#define CHUNK 16384        // edges per workgroup in hist/bin
#define THREADS 256

typedef float vf4 __attribute__((ext_vector_type(4)));
typedef int vi4 __attribute__((ext_vector_type(4)));

// ---------------- K0: per-wg histogram -> counts[w*NB + b] ----------------
__global__ __launch_bounds__(THREADS) void hist_kernel(
    const int* __restrict__ tgt, int e_lo, int e_hi,
    int* __restrict__ counts) {
  __shared__ int h[NB];
  for (int i = threadIdx.x; i < NB; i += THREADS) h[i] = 0;
  __syncthreads();
  int w = blockIdx.x;
  int base = e_lo + w * CHUNK;
  int end = min(base + CHUNK, e_hi);
  if (end - base == CHUNK) {
    const vi4* tp = (const vi4*)(tgt + base);
    for (int i = threadIdx.x; i < CHUNK / 4; i += THREADS) {
      vi4 t4 = tp[i];
      atomicAdd(&h[t4.x >> BSHIFT], 1);
      atomicAdd(&h[t4.y >> BSHIFT], 1);
      atomicAdd(&h[t4.z >> BSHIFT], 1);
      atomicAdd(&h[t4.w >> BSHIFT], 1);
    }
  } else {
    for (int e = base + (int)threadIdx.x; e < end; e += THREADS)
      atomicAdd(&h[tgt[e] >> BSHIFT], 1);
  }
  __syncthreads();
  int* row = counts + (size_t)w * NB;
  for (int i = threadIdx.x; i < NB; i += THREADS) row[i] = h[i];
}

// ---- S1: per-bucket scan over wgs; counts becomes row prefix (in place) ----
__global__ __launch_bounds__(THREADS) void scan1_kernel(
    int* __restrict__ counts, int nw, int* __restrict__ row_total) {
  __shared__ int part[THREADS];
  int b = blockIdx.x;
  int per = (nw + THREADS - 1) / THREADS;
  int w0 = threadIdx.x * per;
  int w1 = min(w0 + per, nw);
  int s = 0;
  for (int w = w0; w < w1; ++w) s += counts[(size_t)w * NB + b];
  part[threadIdx.x] = s;
  __syncthreads();
  for (int off = 1; off < THREADS; off <<= 1) {
    int v = (threadIdx.x >= off) ? part[threadIdx.x - off] : 0;
    __syncthreads();
    part[threadIdx.x] += v;
    __syncthreads();
  }
  int run = part[threadIdx.x] - s;  // exclusive base for this thread's range
  for (int w = w0; w < w1; ++w) {
    int v = counts[(size_t)w * NB + b];
    counts[(size_t)w * NB + b] = run;
    run += v;
  }
  if (threadIdx.x == THREADS - 1) row_total[b] = part[THREADS - 1];
}

// ---- S2: exclusive scan of row_total[NB] -> bucket_base[NB] ----------------
__global__ __launch_bounds__(THREADS) void scan2_kernel(
    const int* __restrict__ row_total, int* __restrict__ bucket_base) {
  __shared__ int part[THREADS];
  int i0 = threadIdx.x * 4;
  int a = row_total[i0], b = row_total[i0 + 1], c = row_total[i0 + 2],
      d = row_total[i0 + 3];
  int s = a + b + c + d;
  part[threadIdx.x] = s;
  __syncthreads();
  for (int off = 1; off < THREADS; off <<= 1) {
    int v = (threadIdx.x >= off) ? part[threadIdx.x - off] : 0;
    __syncthreads();
    part[threadIdx.x] += v;
    __syncthreads();
  }
  int base = part[threadIdx.x] - s;
  bucket_base[i0] = base;
  bucket_base[i0 + 1] = base + a;
  bucket_base[i0 + 2] = base + a + b;
  bucket_base[i0 + 3] = base + a + b + c;
}

// ---------------- K1: LDS counting sort -> coalesced record emit ------------
__global__ __launch_bounds__(THREADS) void bin_kernel(
    const int* __restrict__ tgt, const float* __restrict__ eattr,
    int e_lo, int e_hi, const int* __restrict__ rowpref,  // counts after S1
    const int* __restrict__ bucket_base, vf4* __restrict__ records) {
  __shared__ int h[NB];        // hist, then cursor
  __shared__ int excl[NB];     // local exclusive prefix
  __shared__ int wb[NB];       // global slot base for this wg, per bucket
  __shared__ int part[THREADS];
  __shared__ unsigned short inv[CHUNK];  // sorted slot -> local edge id

  int w = blockIdx.x;
  int base = e_lo + w * CHUNK;
  int end = min(base + CHUNK, e_hi);
  int m = end - base;
  if (m <= 0) return;

  // P1: histogram
  for (int i = threadIdx.x; i < NB; i += THREADS) h[i] = 0;
  __syncthreads();
  if (m == CHUNK) {
    const vi4* tp = (const vi4*)(tgt + base);
    for (int i = threadIdx.x; i < CHUNK / 4; i += THREADS) {
      vi4 t4 = tp[i];
      atomicAdd(&h[t4.x >> BSHIFT], 1);
      atomicAdd(&h[t4.y >> BSHIFT], 1);
      atomicAdd(&h[t4.z >> BSHIFT], 1);
      atomicAdd(&h[t4.w >> BSHIFT], 1);
    }
  } else {
    for (int e = base + (int)threadIdx.x; e < end; e += THREADS)
      atomicAdd(&h[tgt[e] >> BSHIFT], 1);
  }
  __syncthreads();

  // P2: block scan of h -> excl; wb = bucket_base + my row prefix
  int i0 = threadIdx.x * 4;
  int a = h[i0], b = h[i0 + 1], c = h[i0 + 2], d = h[i0 + 3];
  int s = a + b + c + d;
  part[threadIdx.x] = s;
  __syncthreads();
  for (int off = 1; off < THREADS; off <<= 1) {
    int v = (threadIdx.x >= off) ? part[threadIdx.x - off] : 0;
    __syncthreads();
    part[threadIdx.x] += v;
    __syncthreads();
  }
  int eb = part[threadIdx.x] - s;
  excl[i0] = eb;
  excl[i0 + 1] = eb + a;
  excl[i0 + 2] = eb + a + b;
  excl[i0 + 3] = eb + a + b + c;
  const int* myrow = rowpref + (size_t)w * NB;
  wb[i0] = bucket_base[i0] + myrow[i0];
  wb[i0 + 1] = bucket_base[i0 + 1] + myrow[i0 + 1];
  wb[i0 + 2] = bucket_base[i0 + 2] + myrow[i0 + 2];
  wb[i0 + 3] = bucket_base[i0 + 3] + myrow[i0 + 3];
  __syncthreads();

  // P3: rank -> inv permutation (cursor in h, re-initialized from excl)
  for (int i = threadIdx.x; i < NB; i += THREADS) h[i] = excl[i];
  __syncthreads();
  for (int e = base + (int)threadIdx.x; e < end; e += THREADS) {
    int t = tgt[e];  // L1/L2 hit (just read)
    int sp = atomicAdd(&h[t >> BSHIFT], 1);
    inv[sp] = (unsigned short)(e - base);
  }
  __syncthreads();

  // P4: emit records in sorted order -> coalesced full-line writes
  for (int sidx = threadIdx.x; sidx < m; sidx += THREADS) {
    int el = inv[sidx];
    int e = base + el;
    int t = tgt[e];  // L2 gather
    int bk = t >> BSHIFT;
    int slot = wb[bk] + (sidx - excl[bk]);
    const float* ep = eattr + (size_t)e * 3;
    vf4 r;
    r.x = ep[0];
    r.y = ep[1];
    r.z = ep[2];
    r.w = __int_as_float(t);
    records[slot] = r;
  }
}

// ---------------- K2: per-bucket LDS aggregation -> table[N,4] --------------
__global__ __launch_bounds__(THREADS) void agg_kernel(
    const vf4* __restrict__ records, const int* __restrict__ bucket_base,
    const int* __restrict__ row_total, vf4* __restrict__ table, int n_nodes,
    int first_chunk) {
  __shared__ float acc[BNODES * 3];  // 6 KB
  for (int i = threadIdx.x; i < BNODES * 3; i += THREADS) acc[i] = 0.f;
  __syncthreads();
  int b = blockIdx.x;
  int cnt = row_total[b];
  int rbase = bucket_base[b];
  int n0 = b << BSHIFT;
  for (int i = threadIdx.x; i < cnt; i += THREADS) {
    vf4 r = records[rbase + i];  // coalesced 16 B/lane
    int local = __float_as_int(r.w) - n0;
    atomicAdd(&acc[local * 3 + 0], r.x);
    atomicAdd(&acc[local * 3 + 1], r.y);
    atomicAdd(&acc[local * 3 + 2], r.z);
  }
  __syncthreads();
  int nn = min(BNODES, n_nodes - n0);
  for (int i = threadIdx.x; i < nn; i += THREADS) {
    vf4 o;
    o.x = acc[i * 3 + 0];
    o.y = acc[i * 3 + 1];
    o.z = acc[i * 3 + 2];
    o.w = 0.f;
    if (!first_chunk) {
      vf4 p = table[n0 + i];
      o.x += p.x;
      o.y += p.y;
      o.z += p.z;
    }
    table[n0 + i] = o;
  }
}

// ---------------- fallback scatter (tiny ws only) ---------------------------
__global__ __launch_bounds__(THREADS) void scatter_dev_kernel(
    const int* __restrict__ tgt, const float* __restrict__ eattr,
    float* __restrict__ agg, int n_edges) {
  int e = blockIdx.x * blockDim.x + threadIdx.x;
  if (e >= n_edges) return;
  int d = tgt[e];
  atomicAdd(&agg[d * 4 + 0], eattr[(size_t)e * 3 + 0]);
  atomicAdd(&agg[d * 4 + 1], eattr[(size_t)e * 3 + 1]);
  atomicAdd(&agg[d * 4 + 2], eattr[(size_t)e * 3 + 2]);
}

// ---------------- K3: per-node MLP, fully unrolled --------------------------
__global__ __launch_bounds__(THREADS) void mlp_kernel(
    const float* __restrict__ va,   // [N,2]
    const vf4* __restrict__ table,  // [N,4] (x3 used)
    const float* __restrict__ W1, const float* __restrict__ b1,
    const float* __restrict__ W2, const float* __restrict__ b2,
    const float* __restrict__ W3, const float* __restrict__ b3,
    float* __restrict__ out, int n) {
  int i = blockIdx.x * blockDim.x + threadIdx.x;
  if (i >= n) return;

  float x[5];
  float2 v = ((const float2*)va)[i];
  vf4 t = table[i];
  x[0] = v.x;
  x[1] = v.y;
  x[2] = t.x;
  x[3] = t.y;
  x[4] = t.z;

  float h1[50];
#pragma unroll
  for (int j = 0; j < 50; ++j) {
    float s = b1[j];
#pragma unroll
    for (int k = 0; k < 5; ++k) s = fmaf(W1[j * 5 + k], x[k], s);
    h1[j] = fmaxf(s, 0.0f);
  }

  float h2[20];
#pragma unroll
  for (int j = 0; j < 20; ++j) {
    float s = b2[j];
#pragma unroll
    for (int k = 0; k < 50; ++k) s = fmaf(W2[j * 50 + k], h1[k], s);
    h2[j] = fmaxf(s, 0.0f);
  }

  float s = b3[0];
#pragma unroll
  for (int k = 0; k < 20; ++k) s = fmaf(W3[k], h2[k], s);
  out[i] = s;
}

extern "C" void kernel_launch(void* const* d_in, const int* in_sizes, int n_in,
                              void* d_out, int out_size, void* d_ws, size_t ws_size,
                              hipStream_t stream) {
  const float* vertex_attr = (const float*)d_in[0];
  const int* edge_index = (const int*)d_in[1];  // [2, E] int32
  const float* edge_attr = (const float*)d_in[2];
  const float* W1 = (const float*)d_in[3];
  const float* b1 = (const float*)d_in[4];
  const float* W2 = (const float*)d_in[5];
  const float* b2 = (const float*)d_in[6];
  const float* W3 = (const float*)d_in[7];
  const float* b3 = (const float*)d_in[8];
  float* out = (float*)d_out;

  const int n_nodes = in_sizes[0] / 2;   // V_DIM = 2
  const int n_edges = in_sizes[2] / 3;   // E_DIM = 3
  const int* tgt = edge_index + n_edges; // row 1 = targets

  const int nb_rt = (n_nodes + BNODES - 1) >> BSHIFT;  // runtime buckets
  const int nw_max = (n_edges + CHUNK - 1) / CHUNK;

  // ws layout: [table N*4 f32][row_total NB][bucket_base NB][counts nw_max*NB]
  //            [records ...]
  char* ws = (char*)d_ws;
  const size_t table_bytes = (size_t)n_nodes * 4 * sizeof(float);
  vf4* table = (vf4*)ws;
  size_t off = (table_bytes + 255) & ~(size_t)255;
  int* row_total = (int*)(ws + off);
  int* bucket_base = row_total + NB;
  int* counts = bucket_base + NB;
  size_t rec_off =
      (off + (2 * NB + (size_t)nw_max * NB) * sizeof(int) + 255) & ~(size_t)255;
  const size_t rec_space = (ws_size > rec_off) ? (ws_size - rec_off) : 0;
  size_t cap_edges = (rec_space / sizeof(vf4) / CHUNK) * CHUNK;
  vf4* records = (vf4*)(ws + rec_off);

  const int mlp_blocks = (n_nodes + THREADS - 1) / THREADS;

  if (nb_rt <= NB && cap_edges >= (size_t)CHUNK) {
    int nchunk = (int)(((size_t)n_edges + cap_edges - 1) / cap_edges);
    if (nchunk < 1) nchunk = 1;
    int ce = (n_edges + nchunk - 1) / nchunk;
    ce = ((ce + CHUNK - 1) / CHUNK) * CHUNK;  // CHUNK-aligned chunk size
    for (int c = 0; c < nchunk; ++c) {
      const int e_lo = c * ce;
      if (e_lo >= n_edges) break;
      const int e_hi = min(n_edges, e_lo + ce);
      const int nw = (e_hi - e_lo + CHUNK - 1) / CHUNK;
      hist_kernel<<<nw, THREADS, 0, stream>>>(tgt, e_lo, e_hi, counts);
      scan1_kernel<<<NB, THREADS, 0, stream>>>(counts, nw, row_total);
      scan2_kernel<<<1, THREADS, 0, stream>>>(row_total, bucket_base);
      bin_kernel<<<nw, THREADS, 0, stream>>>(tgt, edge_attr, e_lo, e_hi,
                                             counts, bucket_base, records);
      agg_kernel<<<nb_rt, THREADS, 0, stream>>>(records, bucket_base,
                                                row_total, table, n_nodes,
                                                c == 0 ? 1 : 0);
    }
  } else {
    hipMemsetAsync(table, 0, table_bytes, stream);
    const int nblk = (n_edges + THREADS - 1) / THREADS;
    scatter_dev_kernel<<<nblk, THREADS, 0, stream>>>(tgt, edge_attr,
                                                     (float*)table, n_edges);
  }

  mlp_kernel<<<mlp_blocks, THREADS, 0, stream>>>(
      vertex_attr, table, W1, b1, W2, b2, W3, b3, out, n_nodes);
}

// Round 6
// 1087.866 us; speedup vs baseline: 1.0214x; 1.0214x over previous
//
#include <hip/hip_runtime.h>
#include <stdint.h>

// N_NODES=500000, N_EDGES=16000000, V_DIM=2, E_DIM=3. MLP: 5->50->20->1.
//
// R4/R5 lessons: (a) global fp32 atomics = 32B memory-side txn @~20.5G/s ->
// dead. (b) Full bucket-sort write side is fine (269MB for 256MB of records)
// but the sorted-order eattr GATHER thrashes L2 (1.49GB fetch). So: COARSE
// multisplit only. 2048-node super-buckets (245 of them): a wg can own a
// whole super-bucket's 24KB LDS accumulator, so records never need to be
// sorted finer. Split pass runs in FORWARD edge order: coalesced reads,
// and writes are sequential appends to 245 streams -> only each stream's
// 64B tail line is live in L2 (122 wgs/XCD * 245 * 64B ~ 1.9MB) -> full-line
// evictions, no gather, no amplification. Agg pass fuses the MLP (wg owns
// its node range exclusively) -> no table, no separate MLP dispatch.
// Span bookkeeping is the proven deterministic hist -> two-level scan.

#define SB_SHIFT 11     // 2048 nodes per super-bucket
#define SB_NODES 2048
#define NSB 256         // max super-buckets -> n_nodes <= 524288
#define CHUNK 16384     // edges per wg in hist/split
#define THREADS 256

typedef float vf4 __attribute__((ext_vector_type(4)));
typedef int vi4 __attribute__((ext_vector_type(4)));

// ---------------- K0: per-wg histogram -> counts[w*NSB + s] ----------------
__global__ __launch_bounds__(THREADS) void hist_kernel(
    const int* __restrict__ tgt, int n_edges, int* __restrict__ counts) {
  __shared__ int h[NSB];
  for (int i = threadIdx.x; i < NSB; i += THREADS) h[i] = 0;
  __syncthreads();
  int w = blockIdx.x;
  int base = w * CHUNK;
  int end = min(base + CHUNK, n_edges);
  if (end - base == CHUNK) {
    const vi4* tp = (const vi4*)(tgt + base);
    for (int i = threadIdx.x; i < CHUNK / 4; i += THREADS) {
      vi4 t4 = tp[i];
      atomicAdd(&h[t4.x >> SB_SHIFT], 1);
      atomicAdd(&h[t4.y >> SB_SHIFT], 1);
      atomicAdd(&h[t4.z >> SB_SHIFT], 1);
      atomicAdd(&h[t4.w >> SB_SHIFT], 1);
    }
  } else {
    for (int e = base + (int)threadIdx.x; e < end; e += THREADS)
      atomicAdd(&h[tgt[e] >> SB_SHIFT], 1);
  }
  __syncthreads();
  int* row = counts + (size_t)w * NSB;
  for (int i = threadIdx.x; i < NSB; i += THREADS) row[i] = h[i];
}

// ---- S1: per-super-bucket scan over wgs; counts -> row prefix (in place) ---
__global__ __launch_bounds__(THREADS) void scan1_kernel(
    int* __restrict__ counts, int nw, int* __restrict__ row_total) {
  __shared__ int part[THREADS];
  int b = blockIdx.x;
  int per = (nw + THREADS - 1) / THREADS;
  int w0 = threadIdx.x * per;
  int w1 = min(w0 + per, nw);
  int s = 0;
  for (int w = w0; w < w1; ++w) s += counts[(size_t)w * NSB + b];
  part[threadIdx.x] = s;
  __syncthreads();
  for (int off = 1; off < THREADS; off <<= 1) {
    int v = (threadIdx.x >= off) ? part[threadIdx.x - off] : 0;
    __syncthreads();
    part[threadIdx.x] += v;
    __syncthreads();
  }
  int run = part[threadIdx.x] - s;
  for (int w = w0; w < w1; ++w) {
    int v = counts[(size_t)w * NSB + b];
    counts[(size_t)w * NSB + b] = run;
    run += v;
  }
  if (threadIdx.x == THREADS - 1) row_total[b] = part[THREADS - 1];
}

// ---- S2: exclusive scan of row_total[NSB] -> sb_base[NSB] ------------------
__global__ __launch_bounds__(THREADS) void scan2_kernel(
    const int* __restrict__ row_total, int* __restrict__ sb_base) {
  __shared__ int part[THREADS];
  int v = row_total[threadIdx.x];  // NSB == THREADS
  part[threadIdx.x] = v;
  __syncthreads();
  for (int off = 1; off < THREADS; off <<= 1) {
    int u = (threadIdx.x >= off) ? part[threadIdx.x - off] : 0;
    __syncthreads();
    part[threadIdx.x] += u;
    __syncthreads();
  }
  sb_base[threadIdx.x] = part[threadIdx.x] - v;
}

// ---------------- K1: forward-order multisplit into 245 streams -------------
__global__ __launch_bounds__(THREADS) void split_kernel(
    const int* __restrict__ tgt, const float* __restrict__ eattr, int n_edges,
    const int* __restrict__ rowpref,  // counts after S1
    const int* __restrict__ sb_base, vf4* __restrict__ records) {
  __shared__ int cur[NSB];  // global append cursor per super-bucket
  int w = blockIdx.x;
  const int* myrow = rowpref + (size_t)w * NSB;
  for (int i = threadIdx.x; i < NSB; i += THREADS)
    cur[i] = sb_base[i] + myrow[i];
  __syncthreads();
  int base = w * CHUNK;
  int end = min(base + CHUNK, n_edges);

  if (end - base == CHUNK) {
    const vi4* tp = (const vi4*)(tgt + base);
    for (int i = threadIdx.x; i < CHUNK / 4; i += THREADS) {
      vi4 t4 = tp[i];
      const vf4* ep = (const vf4*)(eattr + (size_t)(base + i * 4) * 3);
      vf4 a = ep[0], b = ep[1], c = ep[2];
      vf4 r;
      int slot;
      slot = atomicAdd(&cur[t4.x >> SB_SHIFT], 1);
      r.x = a.x; r.y = a.y; r.z = a.z; r.w = __int_as_float(t4.x);
      records[slot] = r;
      slot = atomicAdd(&cur[t4.y >> SB_SHIFT], 1);
      r.x = a.w; r.y = b.x; r.z = b.y; r.w = __int_as_float(t4.y);
      records[slot] = r;
      slot = atomicAdd(&cur[t4.z >> SB_SHIFT], 1);
      r.x = b.z; r.y = b.w; r.z = c.x; r.w = __int_as_float(t4.z);
      records[slot] = r;
      slot = atomicAdd(&cur[t4.w >> SB_SHIFT], 1);
      r.x = c.y; r.y = c.z; r.z = c.w; r.w = __int_as_float(t4.w);
      records[slot] = r;
    }
  } else {
    for (int e = base + (int)threadIdx.x; e < end; e += THREADS) {
      int t = tgt[e];
      int slot = atomicAdd(&cur[t >> SB_SHIFT], 1);
      const float* ep = eattr + (size_t)e * 3;
      vf4 r;
      r.x = ep[0]; r.y = ep[1]; r.z = ep[2]; r.w = __int_as_float(t);
      records[slot] = r;
    }
  }
}

// -------- K2: per-super-bucket LDS aggregation + fused MLP -> out -----------
__global__ __launch_bounds__(THREADS) void agg_mlp_kernel(
    const vf4* __restrict__ records, const int* __restrict__ sb_base,
    const int* __restrict__ row_total, const float* __restrict__ va,
    const float* __restrict__ W1, const float* __restrict__ b1,
    const float* __restrict__ W2, const float* __restrict__ b2,
    const float* __restrict__ W3, const float* __restrict__ b3,
    float* __restrict__ out, int n_nodes) {
  __shared__ float acc[SB_NODES * 3];  // 24 KB
  for (int i = threadIdx.x; i < SB_NODES * 3; i += THREADS) acc[i] = 0.f;
  __syncthreads();
  int b = blockIdx.x;
  int cnt = row_total[b];
  int rbase = sb_base[b];
  int n0 = b << SB_SHIFT;
  for (int i = threadIdx.x; i < cnt; i += THREADS) {
    vf4 r = records[rbase + i];  // coalesced 16 B/lane
    int local = __float_as_int(r.w) - n0;
    atomicAdd(&acc[local * 3 + 0], r.x);
    atomicAdd(&acc[local * 3 + 1], r.y);
    atomicAdd(&acc[local * 3 + 2], r.z);
  }
  __syncthreads();

  int nn = min(SB_NODES, n_nodes - n0);
  for (int local = threadIdx.x; local < nn; local += THREADS) {
    int i = n0 + local;
    float x[5];
    float2 v = ((const float2*)va)[i];
    x[0] = v.x;
    x[1] = v.y;
    x[2] = acc[local * 3 + 0];
    x[3] = acc[local * 3 + 1];
    x[4] = acc[local * 3 + 2];

    float h1[50];
#pragma unroll
    for (int j = 0; j < 50; ++j) {
      float s = b1[j];
#pragma unroll
      for (int k = 0; k < 5; ++k) s = fmaf(W1[j * 5 + k], x[k], s);
      h1[j] = fmaxf(s, 0.0f);
    }
    float h2[20];
#pragma unroll
    for (int j = 0; j < 20; ++j) {
      float s = b2[j];
#pragma unroll
      for (int k = 0; k < 50; ++k) s = fmaf(W2[j * 50 + k], h1[k], s);
      h2[j] = fmaxf(s, 0.0f);
    }
    float s = b3[0];
#pragma unroll
    for (int k = 0; k < 20; ++k) s = fmaf(W3[k], h2[k], s);
    out[i] = s;
  }
}

// ---------------- fallback (tiny ws): direct device atomics -----------------
__global__ __launch_bounds__(THREADS) void scatter_dev_kernel(
    const int* __restrict__ tgt, const float* __restrict__ eattr,
    float* __restrict__ agg, int n_edges) {
  int e = blockIdx.x * blockDim.x + threadIdx.x;
  if (e >= n_edges) return;
  int d = tgt[e];
  atomicAdd(&agg[d * 4 + 0], eattr[(size_t)e * 3 + 0]);
  atomicAdd(&agg[d * 4 + 1], eattr[(size_t)e * 3 + 1]);
  atomicAdd(&agg[d * 4 + 2], eattr[(size_t)e * 3 + 2]);
}

__global__ __launch_bounds__(THREADS) void mlp_kernel(
    const float* __restrict__ va, const vf4* __restrict__ table,
    const float* __restrict__ W1, const float* __restrict__ b1,
    const float* __restrict__ W2, const float* __restrict__ b2,
    const float* __restrict__ W3, const float* __restrict__ b3,
    float* __restrict__ out, int n) {
  int i = blockIdx.x * blockDim.x + threadIdx.x;
  if (i >= n) return;
  float x[5];
  float2 v = ((const float2*)va)[i];
  vf4 t = table[i];
  x[0] = v.x; x[1] = v.y; x[2] = t.x; x[3] = t.y; x[4] = t.z;
  float h1[50];
#pragma unroll
  for (int j = 0; j < 50; ++j) {
    float s = b1[j];
#pragma unroll
    for (int k = 0; k < 5; ++k) s = fmaf(W1[j * 5 + k], x[k], s);
    h1[j] = fmaxf(s, 0.0f);
  }
  float h2[20];
#pragma unroll
  for (int j = 0; j < 20; ++j) {
    float s = b2[j];
#pragma unroll
    for (int k = 0; k < 50; ++k) s = fmaf(W2[j * 50 + k], h1[k], s);
    h2[j] = fmaxf(s, 0.0f);
  }
  float s = b3[0];
#pragma unroll
  for (int k = 0; k < 20; ++k) s = fmaf(W3[k], h2[k], s);
  out[i] = s;
}

extern "C" void kernel_launch(void* const* d_in, const int* in_sizes, int n_in,
                              void* d_out, int out_size, void* d_ws, size_t ws_size,
                              hipStream_t stream) {
  const float* vertex_attr = (const float*)d_in[0];
  const int* edge_index = (const int*)d_in[1];  // [2, E] int32
  const float* edge_attr = (const float*)d_in[2];
  const float* W1 = (const float*)d_in[3];
  const float* b1 = (const float*)d_in[4];
  const float* W2 = (const float*)d_in[5];
  const float* b2 = (const float*)d_in[6];
  const float* W3 = (const float*)d_in[7];
  const float* b3 = (const float*)d_in[8];
  float* out = (float*)d_out;

  const int n_nodes = in_sizes[0] / 2;   // V_DIM = 2
  const int n_edges = in_sizes[2] / 3;   // E_DIM = 3
  const int* tgt = edge_index + n_edges; // row 1 = targets

  const int nsb_rt = (n_nodes + SB_NODES - 1) >> SB_SHIFT;
  const int nw = (n_edges + CHUNK - 1) / CHUNK;

  // ws layout: [row_total NSB][sb_base NSB][counts nw*NSB][records n_edges]
  char* ws = (char*)d_ws;
  int* row_total = (int*)ws;
  int* sb_base = row_total + NSB;
  int* counts = sb_base + NSB;
  size_t rec_off =
      ((2 * NSB + (size_t)nw * NSB) * sizeof(int) + 255) & ~(size_t)255;
  vf4* records = (vf4*)(ws + rec_off);
  const size_t need = rec_off + (size_t)n_edges * sizeof(vf4);

  if (nsb_rt <= NSB && ws_size >= need) {
    hist_kernel<<<nw, THREADS, 0, stream>>>(tgt, n_edges, counts);
    scan1_kernel<<<NSB, THREADS, 0, stream>>>(counts, nw, row_total);
    scan2_kernel<<<1, THREADS, 0, stream>>>(row_total, sb_base);
    split_kernel<<<nw, THREADS, 0, stream>>>(tgt, edge_attr, n_edges, counts,
                                             sb_base, records);
    agg_mlp_kernel<<<nsb_rt, THREADS, 0, stream>>>(
        records, sb_base, row_total, vertex_attr, W1, b1, W2, b2, W3, b3, out,
        n_nodes);
  } else {
    // fallback: table at ws start, device atomics (slow but correct)
    vf4* table = (vf4*)ws;
    hipMemsetAsync(table, 0, (size_t)n_nodes * sizeof(vf4), stream);
    const int nblk = (n_edges + THREADS - 1) / THREADS;
    scatter_dev_kernel<<<nblk, THREADS, 0, stream>>>(tgt, edge_attr,
                                                     (float*)table, n_edges);
    mlp_kernel<<<(n_nodes + THREADS - 1) / THREADS, THREADS, 0, stream>>>(
        vertex_attr, table, W1, b1, W2, b2, W3, b3, out, n_nodes);
  }
}

// Round 7
// 737.093 us; speedup vs baseline: 1.5075x; 1.4759x over previous
//
#include <hip/hip_runtime.h>
#include <stdint.h>

// N_NODES=500000, N_EDGES=16000000, V_DIM=2, E_DIM=3. MLP: 5->50->20->1.
//
// Lessons so far:
//  R1/R3: per-edge global fp32 atomics = 32B memory-side txn @ ~20.5G/s. Dead.
//  R5: in-wg LDS counting sort gives efficient coalesced record WRITES
//      (269MB for 256MB), but sorted-order eattr gather thrashed L2 (1.5GB).
//  R6: forward-order scatter fixed the gather but the 16M scattered 16B
//      stores are L2-transaction-bound (~64 lines touched per wave); and a
//      245-wg agg kernel sat at 11.5% occupancy (latency-bound).
// This round: LDS sort + LDS-staged eattr (no gather, coalesced emit),
// compressed 12B+2B records, SPLIT=4 agg partials for occupancy, then a
// reduce+MLP kernel.

#define SB_SHIFT 11      // 2048 nodes per super-bucket
#define SB_NODES 2048
#define NSB 256          // max super-buckets -> n_nodes <= 524288
#define CHUNK 4096       // edges per wg in hist/bin
#define TB 512           // bin/agg threads (8 waves)
#define THREADS 256
#define SPLIT 4          // record-range splits per super-bucket in agg

typedef float vf4 __attribute__((ext_vector_type(4)));
typedef int vi4 __attribute__((ext_vector_type(4)));

// ---------------- K0: per-wg histogram -> counts[w*NSB + s] ----------------
__global__ __launch_bounds__(THREADS) void hist_kernel(
    const int* __restrict__ tgt, int n_edges, int* __restrict__ counts) {
  __shared__ int h[NSB];
  for (int i = threadIdx.x; i < NSB; i += THREADS) h[i] = 0;
  __syncthreads();
  int w = blockIdx.x;
  int base = w * CHUNK;
  int end = min(base + CHUNK, n_edges);
  if (end - base == CHUNK) {
    const vi4* tp = (const vi4*)(tgt + base);
    for (int i = threadIdx.x; i < CHUNK / 4; i += THREADS) {
      vi4 t4 = tp[i];
      atomicAdd(&h[t4.x >> SB_SHIFT], 1);
      atomicAdd(&h[t4.y >> SB_SHIFT], 1);
      atomicAdd(&h[t4.z >> SB_SHIFT], 1);
      atomicAdd(&h[t4.w >> SB_SHIFT], 1);
    }
  } else {
    for (int e = base + (int)threadIdx.x; e < end; e += THREADS)
      atomicAdd(&h[tgt[e] >> SB_SHIFT], 1);
  }
  __syncthreads();
  int* row = counts + (size_t)w * NSB;
  for (int i = threadIdx.x; i < NSB; i += THREADS) row[i] = h[i];
}

// ---- S1: per-super-bucket scan over wgs; counts -> row prefix (in place) ---
__global__ __launch_bounds__(THREADS) void scan1_kernel(
    int* __restrict__ counts, int nw, int* __restrict__ row_total) {
  __shared__ int part[THREADS];
  int b = blockIdx.x;
  int per = (nw + THREADS - 1) / THREADS;
  int w0 = threadIdx.x * per;
  int w1 = min(w0 + per, nw);
  int s = 0;
  for (int w = w0; w < w1; ++w) s += counts[(size_t)w * NSB + b];
  part[threadIdx.x] = s;
  __syncthreads();
  for (int off = 1; off < THREADS; off <<= 1) {
    int v = (threadIdx.x >= off) ? part[threadIdx.x - off] : 0;
    __syncthreads();
    part[threadIdx.x] += v;
    __syncthreads();
  }
  int run = part[threadIdx.x] - s;
  for (int w = w0; w < w1; ++w) {
    int v = counts[(size_t)w * NSB + b];
    counts[(size_t)w * NSB + b] = run;
    run += v;
  }
  if (threadIdx.x == THREADS - 1) row_total[b] = part[THREADS - 1];
}

// ---- S2: exclusive scan of row_total[NSB] -> sb_base[NSB] ------------------
__global__ __launch_bounds__(THREADS) void scan2_kernel(
    const int* __restrict__ row_total, int* __restrict__ sb_base) {
  __shared__ int part[THREADS];
  int v = row_total[threadIdx.x];  // NSB == THREADS
  part[threadIdx.x] = v;
  __syncthreads();
  for (int off = 1; off < THREADS; off <<= 1) {
    int u = (threadIdx.x >= off) ? part[threadIdx.x - off] : 0;
    __syncthreads();
    part[threadIdx.x] += u;
    __syncthreads();
  }
  sb_base[threadIdx.x] = part[threadIdx.x] - v;
}

// ------- K1: LDS counting sort + LDS-staged eattr -> coalesced emit ---------
__global__ __launch_bounds__(TB) void bin_kernel(
    const int* __restrict__ tgt, const float* __restrict__ eattr, int n_edges,
    const int* __restrict__ rowpref, const int* __restrict__ sb_base,
    float* __restrict__ rec3, unsigned short* __restrict__ ids) {
  __shared__ float eattr_s[CHUNK * 3];     // 48 KB
  __shared__ unsigned short inv[CHUNK];    // 8 KB
  __shared__ int h[NSB];                   // hist, then cursor
  __shared__ int excl[NSB];
  __shared__ int wb[NSB];
  __shared__ int part[NSB];

  int tid = threadIdx.x;
  int w = blockIdx.x;
  int base = w * CHUNK;
  int end = min(base + CHUNK, n_edges);
  int m = end - base;
  bool full = (m == CHUNK);

  for (int i = tid; i < NSB; i += TB) h[i] = 0;
  __syncthreads();

  // P1: histogram; full-chunk path caches tgt in registers for the rank pass
  vi4 tc[CHUNK / 4 / TB];  // 2 x vi4 = 8 edges/thread
  if (full) {
    const vi4* tp = (const vi4*)(tgt + base);
#pragma unroll
    for (int k = 0; k < CHUNK / 4 / TB; ++k) {
      tc[k] = tp[tid + k * TB];
      atomicAdd(&h[tc[k].x >> SB_SHIFT], 1);
      atomicAdd(&h[tc[k].y >> SB_SHIFT], 1);
      atomicAdd(&h[tc[k].z >> SB_SHIFT], 1);
      atomicAdd(&h[tc[k].w >> SB_SHIFT], 1);
    }
  } else {
    for (int e = base + tid; e < end; e += TB)
      atomicAdd(&h[tgt[e] >> SB_SHIFT], 1);
  }

  // P0: stage this chunk's eattr into LDS (streamed once -> nontemporal)
  {
    const float* src = eattr + (size_t)base * 3;
    int nd = m * 3;
    int nv = nd >> 2;
    const vf4* s4 = (const vf4*)src;
    for (int i = tid; i < nv; i += TB) {
      vf4 v = __builtin_nontemporal_load(s4 + i);
      *(vf4*)(&eattr_s[i * 4]) = v;
    }
    for (int i = (nv << 2) + tid; i < nd; i += TB) eattr_s[i] = src[i];
  }
  __syncthreads();

  // P2: block scan of h -> excl; wb = global span base for this wg
  int myh = 0;
  if (tid < NSB) {
    myh = h[tid];
    part[tid] = myh;
  }
  __syncthreads();
  for (int off = 1; off < NSB; off <<= 1) {
    int v = 0;
    if (tid < NSB && tid >= off) v = part[tid - off];
    __syncthreads();
    if (tid < NSB) part[tid] += v;
    __syncthreads();
  }
  if (tid < NSB) {
    excl[tid] = part[tid] - myh;
    wb[tid] = sb_base[tid] + rowpref[(size_t)w * NSB + tid];
  }
  __syncthreads();

  // P3: rank -> inv (cursor in h, re-initialized from excl)
  for (int i = tid; i < NSB; i += TB) h[i] = excl[i];
  __syncthreads();
  if (full) {
#pragma unroll
    for (int k = 0; k < CHUNK / 4 / TB; ++k) {
      int e0 = (tid + k * TB) * 4;
      int sp;
      sp = atomicAdd(&h[tc[k].x >> SB_SHIFT], 1);
      inv[sp] = (unsigned short)e0;
      sp = atomicAdd(&h[tc[k].y >> SB_SHIFT], 1);
      inv[sp] = (unsigned short)(e0 + 1);
      sp = atomicAdd(&h[tc[k].z >> SB_SHIFT], 1);
      inv[sp] = (unsigned short)(e0 + 2);
      sp = atomicAdd(&h[tc[k].w >> SB_SHIFT], 1);
      inv[sp] = (unsigned short)(e0 + 3);
    }
  } else {
    for (int e = base + tid; e < end; e += TB) {
      int sp = atomicAdd(&h[tgt[e] >> SB_SHIFT], 1);
      inv[sp] = (unsigned short)(e - base);
    }
  }
  __syncthreads();

  // P4: emit in sorted order. Consecutive sidx in a bucket -> consecutive
  // global slots -> coalesced full-line writes. eattr from LDS (no gather);
  // tgt re-read is a 16 KB L1-resident window.
  for (int sidx = tid; sidx < m; sidx += TB) {
    int el = inv[sidx];
    int t = tgt[base + el];
    int bk = t >> SB_SHIFT;
    int slot = wb[bk] + (sidx - excl[bk]);
    float a0 = eattr_s[el * 3 + 0];
    float a1 = eattr_s[el * 3 + 1];
    float a2 = eattr_s[el * 3 + 2];
    size_t o = (size_t)slot * 3;
    rec3[o + 0] = a0;
    rec3[o + 1] = a1;
    rec3[o + 2] = a2;
    ids[slot] = (unsigned short)(t & (SB_NODES - 1));
  }
}

// ---- K2: per-(super-bucket, split) LDS aggregation -> partial tables -------
__global__ __launch_bounds__(TB) void agg_kernel(
    const float* __restrict__ rec3, const unsigned short* __restrict__ ids,
    const int* __restrict__ sb_base, const int* __restrict__ row_total,
    float* __restrict__ partials, size_t pstride) {
  __shared__ float acc[SB_NODES * 3];  // 24 KB
  int tid = threadIdx.x;
  for (int i = tid; i < SB_NODES * 3; i += TB) acc[i] = 0.f;
  __syncthreads();
  int b = blockIdx.x / SPLIT;
  int j = blockIdx.x % SPLIT;
  int cnt = row_total[b];
  int rbase = sb_base[b];
  int q = (cnt + SPLIT - 1) / SPLIT;
  int lo = j * q;
  int hi = min(cnt, lo + q);
  for (int i = lo + tid; i < hi; i += TB) {
    size_t s = (size_t)(rbase + i);
    float r0 = rec3[s * 3 + 0];
    float r1 = rec3[s * 3 + 1];
    float r2 = rec3[s * 3 + 2];
    int local = ids[s];
    atomicAdd(&acc[local * 3 + 0], r0);
    atomicAdd(&acc[local * 3 + 1], r1);
    atomicAdd(&acc[local * 3 + 2], r2);
  }
  __syncthreads();
  float* pj = partials + (size_t)j * pstride + (((size_t)b << SB_SHIFT) * 3);
  for (int i = tid; i < SB_NODES * 3; i += TB) pj[i] = acc[i];
}

// ---------------- K3: reduce SPLIT partials + MLP ---------------------------
__global__ __launch_bounds__(THREADS) void mlp_reduce_kernel(
    const float* __restrict__ va, const float* __restrict__ partials,
    size_t pstride, const float* __restrict__ W1, const float* __restrict__ b1,
    const float* __restrict__ W2, const float* __restrict__ b2,
    const float* __restrict__ W3, const float* __restrict__ b3,
    float* __restrict__ out, int n) {
  int i = blockIdx.x * THREADS + threadIdx.x;
  if (i >= n) return;
  float a0 = 0.f, a1 = 0.f, a2 = 0.f;
#pragma unroll
  for (int j = 0; j < SPLIT; ++j) {
    const float* p = partials + (size_t)j * pstride + (size_t)i * 3;
    a0 += p[0];
    a1 += p[1];
    a2 += p[2];
  }
  float x[5];
  float2 v = ((const float2*)va)[i];
  x[0] = v.x;
  x[1] = v.y;
  x[2] = a0;
  x[3] = a1;
  x[4] = a2;

  float h1[50];
#pragma unroll
  for (int j = 0; j < 50; ++j) {
    float s = b1[j];
#pragma unroll
    for (int k = 0; k < 5; ++k) s = fmaf(W1[j * 5 + k], x[k], s);
    h1[j] = fmaxf(s, 0.0f);
  }
  float h2[20];
#pragma unroll
  for (int j = 0; j < 20; ++j) {
    float s = b2[j];
#pragma unroll
    for (int k = 0; k < 50; ++k) s = fmaf(W2[j * 50 + k], h1[k], s);
    h2[j] = fmaxf(s, 0.0f);
  }
  float s = b3[0];
#pragma unroll
  for (int k = 0; k < 20; ++k) s = fmaf(W3[k], h2[k], s);
  out[i] = s;
}

// ---------------- fallback (tiny ws): direct device atomics -----------------
__global__ __launch_bounds__(THREADS) void scatter_dev_kernel(
    const int* __restrict__ tgt, const float* __restrict__ eattr,
    float* __restrict__ agg, int n_edges) {
  int e = blockIdx.x * blockDim.x + threadIdx.x;
  if (e >= n_edges) return;
  int d = tgt[e];
  atomicAdd(&agg[d * 4 + 0], eattr[(size_t)e * 3 + 0]);
  atomicAdd(&agg[d * 4 + 1], eattr[(size_t)e * 3 + 1]);
  atomicAdd(&agg[d * 4 + 2], eattr[(size_t)e * 3 + 2]);
}

__global__ __launch_bounds__(THREADS) void mlp_table_kernel(
    const float* __restrict__ va, const vf4* __restrict__ table,
    const float* __restrict__ W1, const float* __restrict__ b1,
    const float* __restrict__ W2, const float* __restrict__ b2,
    const float* __restrict__ W3, const float* __restrict__ b3,
    float* __restrict__ out, int n) {
  int i = blockIdx.x * blockDim.x + threadIdx.x;
  if (i >= n) return;
  float x[5];
  float2 v = ((const float2*)va)[i];
  vf4 t = table[i];
  x[0] = v.x; x[1] = v.y; x[2] = t.x; x[3] = t.y; x[4] = t.z;
  float h1[50];
#pragma unroll
  for (int j = 0; j < 50; ++j) {
    float s = b1[j];
#pragma unroll
    for (int k = 0; k < 5; ++k) s = fmaf(W1[j * 5 + k], x[k], s);
    h1[j] = fmaxf(s, 0.0f);
  }
  float h2[20];
#pragma unroll
  for (int j = 0; j < 20; ++j) {
    float s = b2[j];
#pragma unroll
    for (int k = 0; k < 50; ++k) s = fmaf(W2[j * 50 + k], h1[k], s);
    h2[j] = fmaxf(s, 0.0f);
  }
  float s = b3[0];
#pragma unroll
  for (int k = 0; k < 20; ++k) s = fmaf(W3[k], h2[k], s);
  out[i] = s;
}

extern "C" void kernel_launch(void* const* d_in, const int* in_sizes, int n_in,
                              void* d_out, int out_size, void* d_ws, size_t ws_size,
                              hipStream_t stream) {
  const float* vertex_attr = (const float*)d_in[0];
  const int* edge_index = (const int*)d_in[1];  // [2, E] int32
  const float* edge_attr = (const float*)d_in[2];
  const float* W1 = (const float*)d_in[3];
  const float* b1 = (const float*)d_in[4];
  const float* W2 = (const float*)d_in[5];
  const float* b2 = (const float*)d_in[6];
  const float* W3 = (const float*)d_in[7];
  const float* b3 = (const float*)d_in[8];
  float* out = (float*)d_out;

  const int n_nodes = in_sizes[0] / 2;   // V_DIM = 2
  const int n_edges = in_sizes[2] / 3;   // E_DIM = 3
  const int* tgt = edge_index + n_edges; // row 1 = targets

  const int nsb_rt = (n_nodes + SB_NODES - 1) >> SB_SHIFT;
  const int nw = (n_edges + CHUNK - 1) / CHUNK;
  const size_t Np = (size_t)nsb_rt << SB_SHIFT;  // padded node count
  const size_t pstride = Np * 3;                 // floats per partial table

  // ws layout (aligned): [rec3 E*12][ids E*2][row_total][sb_base][counts]
  //                      [partials SPLIT*Np*12]
  char* ws = (char*)d_ws;
  size_t o = 0;
  float* rec3 = (float*)(ws + o);
  o += (size_t)n_edges * 3 * sizeof(float);
  o = (o + 255) & ~(size_t)255;
  unsigned short* ids = (unsigned short*)(ws + o);
  o += (size_t)n_edges * sizeof(unsigned short);
  o = (o + 255) & ~(size_t)255;
  int* row_total = (int*)(ws + o);
  o += NSB * sizeof(int);
  int* sb_base = (int*)(ws + o);
  o += NSB * sizeof(int);
  o = (o + 255) & ~(size_t)255;
  int* counts = (int*)(ws + o);
  o += (size_t)nw * NSB * sizeof(int);
  o = (o + 255) & ~(size_t)255;
  float* partials = (float*)(ws + o);
  o += (size_t)SPLIT * pstride * sizeof(float);
  const size_t need = o;

  if (nsb_rt <= NSB && ws_size >= need) {
    hist_kernel<<<nw, THREADS, 0, stream>>>(tgt, n_edges, counts);
    scan1_kernel<<<NSB, THREADS, 0, stream>>>(counts, nw, row_total);
    scan2_kernel<<<1, THREADS, 0, stream>>>(row_total, sb_base);
    bin_kernel<<<nw, TB, 0, stream>>>(tgt, edge_attr, n_edges, counts, sb_base,
                                      rec3, ids);
    agg_kernel<<<nsb_rt * SPLIT, TB, 0, stream>>>(rec3, ids, sb_base,
                                                  row_total, partials, pstride);
    mlp_reduce_kernel<<<(n_nodes + THREADS - 1) / THREADS, THREADS, 0,
                        stream>>>(vertex_attr, partials, pstride, W1, b1, W2,
                                  b2, W3, b3, out, n_nodes);
  } else {
    vf4* table = (vf4*)ws;
    hipMemsetAsync(table, 0, (size_t)n_nodes * sizeof(vf4), stream);
    const int nblk = (n_edges + THREADS - 1) / THREADS;
    scatter_dev_kernel<<<nblk, THREADS, 0, stream>>>(tgt, edge_attr,
                                                     (float*)table, n_edges);
    mlp_table_kernel<<<(n_nodes + THREADS - 1) / THREADS, THREADS, 0, stream>>>(
        vertex_attr, table, W1, b1, W2, b2, W3, b3, out, n_nodes);
  }
}

// Round 8
// 734.012 us; speedup vs baseline: 1.5139x; 1.0042x over previous
//
#include <hip/hip_runtime.h>
#include <stdint.h>

// N_NODES=500000, N_EDGES=16000000, V_DIM=2, E_DIM=3. MLP: 5->50->20->1.
//
// Lessons:
//  R1/R3: per-edge global fp32 atomics = 32B memory-side txn @ ~20.5G/s. Dead.
//  R5: LDS counting sort gives coalesced record writes; eattr gather is fatal
//      unless staged in LDS (R7 bin does this).
//  R6: 245-wg agg = latency-bound at 11.5% occupancy -> SPLIT partials.
//  R7: agg at VGPR=8 had zero memory-level parallelism (1 outstanding 12B
//      load vs ~600cyc latency) -> 256us with all pipes idle. This round:
//      4-record vectorized loads (3x vf4 + uint2, bases padded to x4) for
//      ILP; counts stored transposed so scan1 reads coalesced rows.

#define SB_SHIFT 11      // 2048 nodes per super-bucket
#define SB_NODES 2048
#define NSB 256          // max super-buckets -> n_nodes <= 524288
#define CHUNK 4096       // edges per wg in hist/bin
#define TB 512           // bin/agg threads (8 waves)
#define THREADS 256
#define SPLIT 4          // record-range splits per super-bucket in agg

typedef float vf4 __attribute__((ext_vector_type(4)));
typedef int vi4 __attribute__((ext_vector_type(4)));
typedef unsigned int vu2 __attribute__((ext_vector_type(2)));

// ------------- K0: per-wg histogram -> counts_T[b*nwpad + w] (transposed) ----
__global__ __launch_bounds__(THREADS) void hist_kernel(
    const int* __restrict__ tgt, int n_edges, int* __restrict__ counts_T,
    int nwpad) {
  __shared__ int h[NSB];
  for (int i = threadIdx.x; i < NSB; i += THREADS) h[i] = 0;
  __syncthreads();
  int w = blockIdx.x;
  int base = w * CHUNK;
  int end = min(base + CHUNK, n_edges);
  if (end - base == CHUNK) {
    const vi4* tp = (const vi4*)(tgt + base);
    for (int i = threadIdx.x; i < CHUNK / 4; i += THREADS) {
      vi4 t4 = tp[i];
      atomicAdd(&h[t4.x >> SB_SHIFT], 1);
      atomicAdd(&h[t4.y >> SB_SHIFT], 1);
      atomicAdd(&h[t4.z >> SB_SHIFT], 1);
      atomicAdd(&h[t4.w >> SB_SHIFT], 1);
    }
  } else {
    for (int e = base + (int)threadIdx.x; e < end; e += THREADS)
      atomicAdd(&h[tgt[e] >> SB_SHIFT], 1);
  }
  __syncthreads();
  // scattered 4B stores, but concurrent wgs (adjacent w) write adjacent
  // addresses in each row -> L2 merges into full lines.
  for (int i = threadIdx.x; i < NSB; i += THREADS)
    counts_T[(size_t)i * nwpad + w] = h[i];
}

// ---- S1: block b scans its contiguous row counts_T[b][0..nw) (in place) ----
__global__ __launch_bounds__(THREADS) void scan1_kernel(
    int* __restrict__ counts_T, int nw, int nwpad, int* __restrict__ row_total) {
  __shared__ int part[THREADS];
  int b = blockIdx.x;
  int* row = counts_T + (size_t)b * nwpad;
  int per = (nw + THREADS - 1) / THREADS;
  int w0 = threadIdx.x * per;
  int w1 = min(w0 + per, nw);
  int s = 0;
  for (int w = w0; w < w1; ++w) s += row[w];
  part[threadIdx.x] = s;
  __syncthreads();
  for (int off = 1; off < THREADS; off <<= 1) {
    int v = (threadIdx.x >= off) ? part[threadIdx.x - off] : 0;
    __syncthreads();
    part[threadIdx.x] += v;
    __syncthreads();
  }
  int run = part[threadIdx.x] - s;
  for (int w = w0; w < w1; ++w) {
    int v = row[w];
    row[w] = run;
    run += v;
  }
  if (threadIdx.x == THREADS - 1) row_total[b] = part[THREADS - 1];
}

// ---- S2: sb_base = exclusive scan of row_total padded up to x4 -------------
__global__ __launch_bounds__(THREADS) void scan2_kernel(
    const int* __restrict__ row_total, int* __restrict__ sb_base) {
  __shared__ int part[THREADS];
  int v = (row_total[threadIdx.x] + 3) & ~3;  // padded span
  part[threadIdx.x] = v;
  __syncthreads();
  for (int off = 1; off < THREADS; off <<= 1) {
    int u = (threadIdx.x >= off) ? part[threadIdx.x - off] : 0;
    __syncthreads();
    part[threadIdx.x] += u;
    __syncthreads();
  }
  sb_base[threadIdx.x] = part[threadIdx.x] - v;  // x4-aligned base
}

// ------- K1: LDS counting sort + LDS-staged eattr -> coalesced emit ---------
__global__ __launch_bounds__(TB) void bin_kernel(
    const int* __restrict__ tgt, const float* __restrict__ eattr, int n_edges,
    const int* __restrict__ rowpref_T, int nwpad,
    const int* __restrict__ sb_base,
    float* __restrict__ rec3, unsigned short* __restrict__ ids) {
  __shared__ float eattr_s[CHUNK * 3];     // 48 KB
  __shared__ unsigned short inv[CHUNK];    // 8 KB
  __shared__ int h[NSB];                   // hist, then cursor
  __shared__ int excl[NSB];
  __shared__ int wb[NSB];
  __shared__ int part[NSB];

  int tid = threadIdx.x;
  int w = blockIdx.x;
  int base = w * CHUNK;
  int end = min(base + CHUNK, n_edges);
  int m = end - base;
  bool full = (m == CHUNK);

  for (int i = tid; i < NSB; i += TB) h[i] = 0;
  __syncthreads();

  // P1: histogram; full-chunk path caches tgt in registers for the rank pass
  vi4 tc[CHUNK / 4 / TB];  // 2 x vi4 = 8 edges/thread
  if (full) {
    const vi4* tp = (const vi4*)(tgt + base);
#pragma unroll
    for (int k = 0; k < CHUNK / 4 / TB; ++k) {
      tc[k] = tp[tid + k * TB];
      atomicAdd(&h[tc[k].x >> SB_SHIFT], 1);
      atomicAdd(&h[tc[k].y >> SB_SHIFT], 1);
      atomicAdd(&h[tc[k].z >> SB_SHIFT], 1);
      atomicAdd(&h[tc[k].w >> SB_SHIFT], 1);
    }
  } else {
    for (int e = base + tid; e < end; e += TB)
      atomicAdd(&h[tgt[e] >> SB_SHIFT], 1);
  }

  // P0: stage this chunk's eattr into LDS
  {
    const float* src = eattr + (size_t)base * 3;
    int nd = m * 3;
    int nv = nd >> 2;
    const vf4* s4 = (const vf4*)src;
    for (int i = tid; i < nv; i += TB) {
      vf4 v = __builtin_nontemporal_load(s4 + i);
      *(vf4*)(&eattr_s[i * 4]) = v;
    }
    for (int i = (nv << 2) + tid; i < nd; i += TB) eattr_s[i] = src[i];
  }
  __syncthreads();

  // P2: block scan of h -> excl; wb = global span base for this wg
  int myh = 0;
  if (tid < NSB) {
    myh = h[tid];
    part[tid] = myh;
  }
  __syncthreads();
  for (int off = 1; off < NSB; off <<= 1) {
    int v = 0;
    if (tid < NSB && tid >= off) v = part[tid - off];
    __syncthreads();
    if (tid < NSB) part[tid] += v;
    __syncthreads();
  }
  if (tid < NSB) {
    excl[tid] = part[tid] - myh;
    wb[tid] = sb_base[tid] + rowpref_T[(size_t)tid * nwpad + w];
  }
  __syncthreads();

  // P3: rank -> inv (cursor in h, re-initialized from excl)
  for (int i = tid; i < NSB; i += TB) h[i] = excl[i];
  __syncthreads();
  if (full) {
#pragma unroll
    for (int k = 0; k < CHUNK / 4 / TB; ++k) {
      int e0 = (tid + k * TB) * 4;
      int sp;
      sp = atomicAdd(&h[tc[k].x >> SB_SHIFT], 1);
      inv[sp] = (unsigned short)e0;
      sp = atomicAdd(&h[tc[k].y >> SB_SHIFT], 1);
      inv[sp] = (unsigned short)(e0 + 1);
      sp = atomicAdd(&h[tc[k].z >> SB_SHIFT], 1);
      inv[sp] = (unsigned short)(e0 + 2);
      sp = atomicAdd(&h[tc[k].w >> SB_SHIFT], 1);
      inv[sp] = (unsigned short)(e0 + 3);
    }
  } else {
    for (int e = base + tid; e < end; e += TB) {
      int sp = atomicAdd(&h[tgt[e] >> SB_SHIFT], 1);
      inv[sp] = (unsigned short)(e - base);
    }
  }
  __syncthreads();

  // P4: emit in sorted order -> coalesced runs; eattr from LDS, tgt from L1.
  for (int sidx = tid; sidx < m; sidx += TB) {
    int el = inv[sidx];
    int t = tgt[base + el];
    int bk = t >> SB_SHIFT;
    int slot = wb[bk] + (sidx - excl[bk]);
    float a0 = eattr_s[el * 3 + 0];
    float a1 = eattr_s[el * 3 + 1];
    float a2 = eattr_s[el * 3 + 2];
    size_t o = (size_t)slot * 3;
    rec3[o + 0] = a0;
    rec3[o + 1] = a1;
    rec3[o + 2] = a2;
    ids[slot] = (unsigned short)(t & (SB_NODES - 1));
  }
}

// ---- K2: per-(SB, split) LDS aggregation, quad-vectorized record loads -----
__global__ __launch_bounds__(TB) void agg_kernel(
    const float* __restrict__ rec3, const unsigned short* __restrict__ ids,
    const int* __restrict__ sb_base, const int* __restrict__ row_total,
    float* __restrict__ partials, size_t pstride) {
  __shared__ float acc[SB_NODES * 3];  // 24 KB
  int tid = threadIdx.x;
  for (int i = tid; i < SB_NODES * 3; i += TB) acc[i] = 0.f;
  __syncthreads();
  int b = blockIdx.x / SPLIT;
  int j = blockIdx.x % SPLIT;
  int cnt = row_total[b];
  int rbase = sb_base[b];  // x4-aligned
  int q = (((cnt + SPLIT - 1) / SPLIT) + 3) & ~3;  // x4 split size
  int lo = j * q;
  int hi = min(cnt, lo + q);
  int len = hi - lo;
  if (len > 0) {
    int nq = len >> 2;  // full quads
    // quad path: 3x vf4 (48B, 16B-aligned since (rbase+lo+4k)%4==0) + uint2
    for (int k = tid; k < nq; k += TB) {
      int s0 = rbase + lo + (k << 2);
      const vf4* rp = (const vf4*)(rec3 + (size_t)s0 * 3);
      vf4 r0 = rp[0];
      vf4 r1 = rp[1];
      vf4 r2 = rp[2];
      vu2 u = *(const vu2*)(ids + s0);
      int l0 = u.x & 0xFFFF;
      int l1 = u.x >> 16;
      int l2 = u.y & 0xFFFF;
      int l3 = u.y >> 16;
      atomicAdd(&acc[l0 * 3 + 0], r0.x);
      atomicAdd(&acc[l0 * 3 + 1], r0.y);
      atomicAdd(&acc[l0 * 3 + 2], r0.z);
      atomicAdd(&acc[l1 * 3 + 0], r0.w);
      atomicAdd(&acc[l1 * 3 + 1], r1.x);
      atomicAdd(&acc[l1 * 3 + 2], r1.y);
      atomicAdd(&acc[l2 * 3 + 0], r1.z);
      atomicAdd(&acc[l2 * 3 + 1], r1.w);
      atomicAdd(&acc[l2 * 3 + 2], r2.x);
      atomicAdd(&acc[l3 * 3 + 0], r2.y);
      atomicAdd(&acc[l3 * 3 + 1], r2.z);
      atomicAdd(&acc[l3 * 3 + 2], r2.w);
    }
    // tail (< 4 records)
    for (int i = lo + (nq << 2) + tid; i < hi; i += TB) {
      size_t s = (size_t)(rbase + i);
      float r0 = rec3[s * 3 + 0];
      float r1 = rec3[s * 3 + 1];
      float r2 = rec3[s * 3 + 2];
      int local = ids[s];
      atomicAdd(&acc[local * 3 + 0], r0);
      atomicAdd(&acc[local * 3 + 1], r1);
      atomicAdd(&acc[local * 3 + 2], r2);
    }
  }
  __syncthreads();
  float* pj = partials + (size_t)j * pstride + (((size_t)b << SB_SHIFT) * 3);
  for (int i = tid; i < SB_NODES * 3; i += TB) pj[i] = acc[i];
}

// ---------------- K3: reduce SPLIT partials + MLP ---------------------------
__global__ __launch_bounds__(THREADS) void mlp_reduce_kernel(
    const float* __restrict__ va, const float* __restrict__ partials,
    size_t pstride, const float* __restrict__ W1, const float* __restrict__ b1,
    const float* __restrict__ W2, const float* __restrict__ b2,
    const float* __restrict__ W3, const float* __restrict__ b3,
    float* __restrict__ out, int n) {
  int i = blockIdx.x * THREADS + threadIdx.x;
  if (i >= n) return;
  float a0 = 0.f, a1 = 0.f, a2 = 0.f;
#pragma unroll
  for (int j = 0; j < SPLIT; ++j) {
    const float* p = partials + (size_t)j * pstride + (size_t)i * 3;
    a0 += p[0];
    a1 += p[1];
    a2 += p[2];
  }
  float x[5];
  float2 v = ((const float2*)va)[i];
  x[0] = v.x;
  x[1] = v.y;
  x[2] = a0;
  x[3] = a1;
  x[4] = a2;

  float h1[50];
#pragma unroll
  for (int j = 0; j < 50; ++j) {
    float s = b1[j];
#pragma unroll
    for (int k = 0; k < 5; ++k) s = fmaf(W1[j * 5 + k], x[k], s);
    h1[j] = fmaxf(s, 0.0f);
  }
  float h2[20];
#pragma unroll
  for (int j = 0; j < 20; ++j) {
    float s = b2[j];
#pragma unroll
    for (int k = 0; k < 50; ++k) s = fmaf(W2[j * 50 + k], h1[k], s);
    h2[j] = fmaxf(s, 0.0f);
  }
  float s = b3[0];
#pragma unroll
  for (int k = 0; k < 20; ++k) s = fmaf(W3[k], h2[k], s);
  out[i] = s;
}

// ---------------- fallback (tiny ws): direct device atomics -----------------
__global__ __launch_bounds__(THREADS) void scatter_dev_kernel(
    const int* __restrict__ tgt, const float* __restrict__ eattr,
    float* __restrict__ agg, int n_edges) {
  int e = blockIdx.x * blockDim.x + threadIdx.x;
  if (e >= n_edges) return;
  int d = tgt[e];
  atomicAdd(&agg[d * 4 + 0], eattr[(size_t)e * 3 + 0]);
  atomicAdd(&agg[d * 4 + 1], eattr[(size_t)e * 3 + 1]);
  atomicAdd(&agg[d * 4 + 2], eattr[(size_t)e * 3 + 2]);
}

__global__ __launch_bounds__(THREADS) void mlp_table_kernel(
    const float* __restrict__ va, const vf4* __restrict__ table,
    const float* __restrict__ W1, const float* __restrict__ b1,
    const float* __restrict__ W2, const float* __restrict__ b2,
    const float* __restrict__ W3, const float* __restrict__ b3,
    float* __restrict__ out, int n) {
  int i = blockIdx.x * blockDim.x + threadIdx.x;
  if (i >= n) return;
  float x[5];
  float2 v = ((const float2*)va)[i];
  vf4 t = table[i];
  x[0] = v.x; x[1] = v.y; x[2] = t.x; x[3] = t.y; x[4] = t.z;
  float h1[50];
#pragma unroll
  for (int j = 0; j < 50; ++j) {
    float s = b1[j];
#pragma unroll
    for (int k = 0; k < 5; ++k) s = fmaf(W1[j * 5 + k], x[k], s);
    h1[j] = fmaxf(s, 0.0f);
  }
  float h2[20];
#pragma unroll
  for (int j = 0; j < 20; ++j) {
    float s = b2[j];
#pragma unroll
    for (int k = 0; k < 50; ++k) s = fmaf(W2[j * 50 + k], h1[k], s);
    h2[j] = fmaxf(s, 0.0f);
  }
  float s = b3[0];
#pragma unroll
  for (int k = 0; k < 20; ++k) s = fmaf(W3[k], h2[k], s);
  out[i] = s;
}

extern "C" void kernel_launch(void* const* d_in, const int* in_sizes, int n_in,
                              void* d_out, int out_size, void* d_ws, size_t ws_size,
                              hipStream_t stream) {
  const float* vertex_attr = (const float*)d_in[0];
  const int* edge_index = (const int*)d_in[1];  // [2, E] int32
  const float* edge_attr = (const float*)d_in[2];
  const float* W1 = (const float*)d_in[3];
  const float* b1 = (const float*)d_in[4];
  const float* W2 = (const float*)d_in[5];
  const float* b2 = (const float*)d_in[6];
  const float* W3 = (const float*)d_in[7];
  const float* b3 = (const float*)d_in[8];
  float* out = (float*)d_out;

  const int n_nodes = in_sizes[0] / 2;   // V_DIM = 2
  const int n_edges = in_sizes[2] / 3;   // E_DIM = 3
  const int* tgt = edge_index + n_edges; // row 1 = targets

  const int nsb_rt = (n_nodes + SB_NODES - 1) >> SB_SHIFT;
  const int nw = (n_edges + CHUNK - 1) / CHUNK;
  const int nwpad = nw;
  const size_t Np = (size_t)nsb_rt << SB_SHIFT;  // padded node count
  const size_t pstride = Np * 3;                 // floats per partial table
  const int rec_cap = n_edges + 4 * NSB;         // slack for x4 base padding

  // ws layout (aligned): [rec3 cap*12][ids cap*2][row_total][sb_base]
  //                      [counts_T NSB*nwpad][partials SPLIT*Np*12]
  char* ws = (char*)d_ws;
  size_t o = 0;
  float* rec3 = (float*)(ws + o);
  o += (size_t)rec_cap * 3 * sizeof(float);
  o = (o + 255) & ~(size_t)255;
  unsigned short* ids = (unsigned short*)(ws + o);
  o += (size_t)rec_cap * sizeof(unsigned short);
  o = (o + 255) & ~(size_t)255;
  int* row_total = (int*)(ws + o);
  o += NSB * sizeof(int);
  int* sb_base = (int*)(ws + o);
  o += NSB * sizeof(int);
  o = (o + 255) & ~(size_t)255;
  int* counts_T = (int*)(ws + o);
  o += (size_t)NSB * nwpad * sizeof(int);
  o = (o + 255) & ~(size_t)255;
  float* partials = (float*)(ws + o);
  o += (size_t)SPLIT * pstride * sizeof(float);
  const size_t need = o;

  if (nsb_rt <= NSB && ws_size >= need) {
    hist_kernel<<<nw, THREADS, 0, stream>>>(tgt, n_edges, counts_T, nwpad);
    scan1_kernel<<<NSB, THREADS, 0, stream>>>(counts_T, nw, nwpad, row_total);
    scan2_kernel<<<1, THREADS, 0, stream>>>(row_total, sb_base);
    bin_kernel<<<nw, TB, 0, stream>>>(tgt, edge_attr, n_edges, counts_T, nwpad,
                                      sb_base, rec3, ids);
    agg_kernel<<<nsb_rt * SPLIT, TB, 0, stream>>>(rec3, ids, sb_base,
                                                  row_total, partials, pstride);
    mlp_reduce_kernel<<<(n_nodes + THREADS - 1) / THREADS, THREADS, 0,
                        stream>>>(vertex_attr, partials, pstride, W1, b1, W2,
                                  b2, W3, b3, out, n_nodes);
  } else {
    vf4* table = (vf4*)ws;
    hipMemsetAsync(table, 0, (size_t)n_nodes * sizeof(vf4), stream);
    const int nblk = (n_edges + THREADS - 1) / THREADS;
    scatter_dev_kernel<<<nblk, THREADS, 0, stream>>>(tgt, edge_attr,
                                                     (float*)table, n_edges);
    mlp_table_kernel<<<(n_nodes + THREADS - 1) / THREADS, THREADS, 0, stream>>>(
        vertex_attr, table, W1, b1, W2, b2, W3, b3, out, n_nodes);
  }
}